// Round 9
// baseline (15423.514 us; speedup 1.0000x reference)
//
#include <hip/hip_runtime.h>
#include <hip/hip_bf16.h>
#include <stdint.h>

// Problem: IN=512, H=2048, OUT=512, T=8192. Gate rows 4H=8192.
// Persistent-RNN: 256 blocks x 256 threads (4 waves), 1 block/CU, [W_ih|W_hh]
// in VGPRs as f16 pairs (160 u32/lane). h exchanged device-wide as
// step-tagged u64 ({f16 pair | step}) via L3/HBM, sc0 sc1 asm polls.
// Round 19 = r17 champion (13.98ms, exact base) + ADAPTIVE PRE-SLEEP.
//   r18 post-mortem (+4%): "contiguous" remap was anti-coalescing (16B at
//   32B stride -> 32 lines/instr vs 16) ~2x poll transactions; throttle
//   3->5 added traffic. LAW: polls stay fully coalesced (16B/lane
//   contiguous); traffic is the sensitive knob. Both reverted.
//   New budget insight: WRITE_SIZE==publishes, FETCH ~ +270MB/run ~= one
//   HBM-side fetch per fresh poll line per step => publish->detect hop is
//   ~900-1000cy (HBM-class), detect ~ 3 sweeps x 1000 + compute 1100 ~=
//   4100cy == measured. Sweeps 1-2 are GUARANTEED misses (ready ~2.2-2.8
//   RTT after step start): pure traffic + RTT-grid quantization.
//   FIX: delay first poll issue by dly sleep-quanta, adapted on `tries`:
//   miss -> dly += 2; clean sweep-1 detect -> probe down 1 every 16th step;
//   cap 44. Equilibrium: detect ~= ready + ~100cy (vs ready + up-to-RTT),
//   ~60% less poll traffic. Pure timing change — correctness untouched.
// LAWS (hard-won, do not revisit):
//   r18: poll loads fully coalesced; don't loosen throttle.
//   r16: publish lockstep via in-loop __syncthreads is LOAD-BEARING; flag/
//     rotation protocols spread publish variance, it feeds forward (+68%).
//   r15: dot2 == pk_fma issue rate; 128 dot2 is the h-dot VALU floor.
//   r14: never exit a spin with un-waited loads; no pipelined 2-set polls
//     (stray set force-drained by barrier vmcnt(0) anyway).
//   r11: __hip_atomic_load(RELAXED,AGENT) does NOT emit sc0 -> stale L1
//     polls. Spin must use asm global_load_dwordx4 sc0 sc1.
//   r7/r9: arch VGPRs cap at 256/wave; 160 weight regs fit ONLY with
//     256-thread blocks; no 512-thread or 320-reg variants.

// ---------------- helpers ----------------

__device__ __forceinline__ uint32_t packf16(float a, float b) {
    // v_cvt_pkrtz_f16_f32: a -> low16, b -> high16 (RTZ)
    auto h = __builtin_amdgcn_cvt_pkrtz(a, b);
    return __builtin_bit_cast(uint32_t, h);
}

__device__ __forceinline__ float dot2h(uint32_t a, uint32_t b, float c) {
    float d;
    asm("v_dot2_f32_f16 %0, %1, %2, %3" : "=v"(d) : "v"(a), "v"(b), "v"(c));
    return d;
}

template <int CTRL>
__device__ __forceinline__ float movdpp(float x) {
    return __int_as_float(__builtin_amdgcn_mov_dpp(__float_as_int(x), CTRL, 0xF, 0xF, true));
}

// acc += shfl_xor(acc,16) via v_permlane16_swap (a'={r0,r0,r2,r2}, b'={r1,r1,r3,r3})
__device__ __forceinline__ float xorsum16(float x) {
#if __has_builtin(__builtin_amdgcn_permlane16_swap)
    auto r = __builtin_amdgcn_permlane16_swap(__float_as_uint(x), __float_as_uint(x), false, false);
    return __uint_as_float(r[0]) + __uint_as_float(r[1]);
#else
    return x + __shfl_xor(x, 16, 64);
#endif
}

// acc += shfl_xor(acc,32) via v_permlane32_swap (a'={lo,lo}, b'={hi,hi})
__device__ __forceinline__ float xorsum32(float x) {
#if __has_builtin(__builtin_amdgcn_permlane32_swap)
    auto r = __builtin_amdgcn_permlane32_swap(__float_as_uint(x), __float_as_uint(x), false, false);
    return __uint_as_float(r[0]) + __uint_as_float(r[1]);
#else
    return x + __shfl_xor(x, 32, 64);
#endif
}

__device__ __forceinline__ float sigm(float x) { return 1.f / (1.f + __expf(-x)); }
__device__ __forceinline__ float tanh_fast(float x) { return 1.f - 2.f / (1.f + __expf(2.f * x)); }

#define ASTORE(p, v) __hip_atomic_store((p), (v), __ATOMIC_RELAXED, __HIP_MEMORY_SCOPE_AGENT)

// Issue two 16B device-scope loads (bypass L1/L2 via sc0 sc1), NO wait.
// Tear-safe: each contained u64 carries its own tag in the low 32 bits.
__device__ __forceinline__ void poll_issue(const unsigned long long* pa,
                                           const unsigned long long* pb,
                                           ulonglong2& ra, ulonglong2& rb) {
    asm volatile(
        "global_load_dwordx4 %0, %2, off sc0 sc1\n\t"
        "global_load_dwordx4 %1, %3, off sc0 sc1"
        : "=v"(ra), "=v"(rb)
        : "v"(pa), "v"(pb)
        : "memory");
    __builtin_amdgcn_sched_barrier(0);  // keep dependent VALU below the issue
}

// Reissue a single 16B half (used by the sticky spin on unmatched halves only).
__device__ __forceinline__ void poll_issue_one(const unsigned long long* p, ulonglong2& r) {
    asm volatile("global_load_dwordx4 %0, %1, off sc0 sc1"
                 : "=v"(r) : "v"(p) : "memory");
}

__device__ __forceinline__ void poll_wait() {
    asm volatile("s_waitcnt vmcnt(0)" ::: "memory");
    __builtin_amdgcn_sched_barrier(0);  // rule #18: stop reg-only hoisting past waitcnt
}

// ---------------- kernel 0: invalidate tags ----------------
__global__ __launch_bounds__(256) void init_hbuf(unsigned long long* hbuf) {
    int i = blockIdx.x * 256 + threadIdx.x;
    if (i < 2048) hbuf[i] = ~0ull;  // tag 0xFFFFFFFF never matches a step index
}

// ---------------- kernel 1: persistent LSTM recurrence ----------------
// Block b owns h indices [8b, 8b+8). Wave q owns rows {hb+2q, hb+2q+1}, ALL 4
// gates (combo c = gate*2 + rowbit). Weights: 160 packed f16 VGPRs/lane
// (k<4 = W_ih, else W_hh remapped: w[c*20+4+4j+i] <-> h pair 256j+4*lane+i).
// Spin: wave q polls pairs [256q,256q+256): lane L watches pairs {256q+2L,
// 256q+2L+1} and {256q+128+2L, +1} via 2 coalesced dwordx4, sticky per-half.
__global__ __launch_bounds__(256, 1) void lstm_persist(const float* __restrict__ seq,
                                                       const float* __restrict__ Wih,
                                                       const float* __restrict__ Whh,
                                                       const float* __restrict__ bih,
                                                       const float* __restrict__ bhh,
                                                       const float* __restrict__ h0,
                                                       const float* __restrict__ c0,
                                                       unsigned long long* hbuf,
                                                       float* __restrict__ hf32) {
    const int b = blockIdx.x, tid = threadIdx.x;
    const int q = tid >> 6, lane = tid & 63;
    const int hb = b * 8;
    const int rb = (lane >> 2) & 1;       // this lane's row within the wave's pair
    const int myrow = hb + 2 * q + rb;

    // ---- preload [W_ih | W_hh] rows for all 4 gates of rows {2q, 2q+1} ----
    uint32_t w[160];
#pragma unroll
    for (int c = 0; c < 8; c++) {
        const int R = (c >> 1) * 2048 + hb + 2 * q + (c & 1);
        const float2* rih = (const float2*)(Wih + (size_t)R * 512);
        const float2* rhh = (const float2*)(Whh + (size_t)R * 2048);
#pragma unroll
        for (int k = 0; k < 4; k++) {
            float2 v = rih[k * 64 + lane];
            w[c * 20 + k] = packf16(v.x, v.y);
        }
        // W_hh remap to match the b128 h-dot: w[c*20+4+4j+i] <-> h pair 256j+4*lane+i
#pragma unroll
        for (int j = 0; j < 4; j++)
#pragma unroll
            for (int i = 0; i < 4; i++) {
                float2 v = rhh[256 * j + 4 * lane + i];
                w[c * 20 + 4 + 4 * j + i] = packf16(v.x, v.y);
            }
    }

    __shared__ alignas(16) uint32_t v_stage[2][1024];  // h_{t-1} pairs, parity double-buffered

    // per-lane (replicated) bias + c state for row `myrow`
    const float bi  = bih[myrow] + bhh[myrow];
    const float bf_ = bih[2048 + myrow] + bhh[2048 + myrow];
    const float bg  = bih[4096 + myrow] + bhh[4096 + myrow];
    const float bo  = bih[6144 + myrow] + bhh[6144 + myrow];
    float c_state = c0[myrow];

    // publish h0 slice with tag 0 (parity 0)
    if (q == 0 && lane < 4) {
        float a = h0[hb + lane * 2], b2 = h0[hb + lane * 2 + 1];
        unsigned long long v = ((unsigned long long)packf16(a, b2) << 32);
        ASTORE(&hbuf[b * 4 + lane], v);
    }

    // prefetch x_0: lane owns x pairs {k*64+lane : k in [0,4)}
    float2 xn[4];
#pragma unroll
    for (int k = 0; k < 4; k++) xn[k] = ((const float2*)seq)[k * 64 + lane];

    int gave_up = 0;
    int dly = 0;  // adaptive pre-sleep, in s_sleep(1) quanta (~64cy each)

    for (int s = 1; s <= 8192; s++) {
        const int t = s - 1, bs = t & 1;
        const uint32_t want = (uint32_t)t;

        // ---- pack x_t (compiler drains the x prefetch here, BEFORE poll issue) ----
        uint32_t x0 = packf16(xn[0].x, xn[0].y), x1 = packf16(xn[1].x, xn[1].y);
        uint32_t x2 = packf16(xn[2].x, xn[2].y), x3 = packf16(xn[3].x, xn[3].y);
        __builtin_amdgcn_sched_barrier(0);  // pin pack (and its waitcnt) above poll issue

        // ---- adaptive pre-sleep: land sweep 1 just after publishes are ready,
        // instead of burning 2 guaranteed-miss sweeps on the ~1000cy RTT grid ----
        for (int i = 0; i < dly; ++i) __builtin_amdgcn_s_sleep(1);

        // ---- poll issue: first sweep's RTT overlaps the x-dot ----
        const unsigned long long* base = hbuf + (bs << 10) + q * 256;
        const unsigned long long* pa = base + 2 * lane;        // pairs 2L, 2L+1
        const unsigned long long* pb = base + 128 + 2 * lane;  // pairs 128+2L, +1
        ulonglong2 ra, rb2;
        poll_issue(pa, pb, ra, rb2);

        // ---- x-part of dot from registers (VALU-only, hides first poll RTT) ----
        float acc[8];
#pragma unroll
        for (int c = 0; c < 8; c++) {
            float a = dot2h(w[c * 20 + 0], x0, 0.f);
            a = dot2h(w[c * 20 + 1], x1, a);
            a = dot2h(w[c * 20 + 2], x2, a);
            acc[c] = dot2h(w[c * 20 + 3], x3, a);
        }

        // ---- distributed spin, sticky halves: once a 16B half's two tags
        // match (monotonic within the step), stop re-loading it; reissue
        // only unmatched halves. Every sweep starts with vmcnt(0); no exit
        // with un-waited loads. ----
        int tries = 0;
        if (!gave_up) {
            bool oka = false, okb = false;
            for (;;) {
                poll_wait();
                oka = oka | (((uint32_t)ra.x == want) & ((uint32_t)ra.y == want));
                okb = okb | (((uint32_t)rb2.x == want) & ((uint32_t)rb2.y == want));
                if (__all(oka & okb)) break;
                if (++tries > (1 << 17)) { gave_up = 1; break; }  // diagnostic fuse
                if (!oka) poll_issue_one(pa, ra);                 // reissue misses only
                if (!okb) poll_issue_one(pb, rb2);
                __builtin_amdgcn_sched_barrier(0);
                if (tries > 2) __builtin_amdgcn_s_sleep(1);       // sleep overlaps RTT
            }
        } else {
            poll_wait();  // loop-top issue acts as the once-per-iter refresh
        }

        // ---- adapt pre-sleep: miss -> grow toward the ready-edge; clean
        // sweep-1 detect -> probe down 1 quantum every 16th step (hysteresis) ----
        if (!gave_up) {
            if (tries == 0) {
                if ((s & 15) == 0 && dly > 0) --dly;
            } else {
                dly += 2;
                if (dly > 44) dly = 44;
            }
        }

        // ---- stage payload -> LDS (identity pair layout: two b64 stores) ----
        {
            uint2* vsa = (uint2*)&v_stage[bs][q * 256 + 2 * lane];
            uint2* vsb = (uint2*)&v_stage[bs][q * 256 + 128 + 2 * lane];
            *vsa = make_uint2((uint32_t)(ra.x >> 32), (uint32_t)(ra.y >> 32));
            *vsb = make_uint2((uint32_t)(rb2.x >> 32), (uint32_t)(rb2.y >> 32));
        }

        __syncthreads();  // B1: v_stage[bs] ready (cheap: nothing in vmcnt)

        // prefetch x_{t+1} AFTER the barrier: drains under the h-dot,
        // off both the spin path and the barrier's vmcnt(0) drain.
        if (s < 8192) {
            const float2* xp = (const float2*)(seq + (size_t)s * 512);
#pragma unroll
            for (int k = 0; k < 4; k++) xn[k] = xp[k * 64 + lane];
        }

        // ---- h-part of dot: 4 quarters x b128; lane L reads pairs 256j+4L+{0..3} ----
#pragma unroll
        for (int j = 0; j < 4; j++) {
            const uint4 hv = *(const uint4*)&v_stage[bs][256 * j + 4 * lane];
#pragma unroll
            for (int c = 0; c < 8; c++) {
                float a = dot2h(w[c * 20 + 4 + 4 * j + 0], hv.x, acc[c]);
                a = dot2h(w[c * 20 + 4 + 4 * j + 1], hv.y, a);
                a = dot2h(w[c * 20 + 4 + 4 * j + 2], hv.z, a);
                acc[c] = dot2h(w[c * 20 + 4 + 4 * j + 3], hv.w, a);
            }
        }

        // ---- fold 8 accs -> 1; DPP/permlane forms (only xor4 keeps DS).
        // Lane L holds combo c(L&7) = 4*(L&1) + 2*((L>>1)&1) + ((L>>2)&1),
        // replicated every 8 lanes ----
#pragma unroll
        for (int j = 0; j < 4; j++) {  // d=1: 8 -> 4 (quad_perm xor1 = 0xB1)
            float lo = acc[j], hi = acc[j + 4];
            float sel = (lane & 1) ? lo : hi;
            float got = movdpp<0xB1>(sel);
            acc[j] = ((lane & 1) ? hi : lo) + got;
        }
#pragma unroll
        for (int j = 0; j < 2; j++) {  // d=2: 4 -> 2 (quad_perm xor2 = 0x4E)
            float lo = acc[j], hi = acc[j + 2];
            float sel = (lane & 2) ? lo : hi;
            float got = movdpp<0x4E>(sel);
            acc[j] = ((lane & 2) ? hi : lo) + got;
        }
        {  // d=4: 2 -> 1 (no DPP form for xor4; keep ds shuffle)
            float lo = acc[0], hi = acc[1];
            float sel = (lane & 4) ? lo : hi;
            float got = __shfl_xor(sel, 4, 64);
            acc[0] = ((lane & 4) ? hi : lo) + got;
        }
        acc[0] += movdpp<0x128>(acc[0]);  // xor8 via row_ror:8
        acc[0] = xorsum16(acc[0]);        // xor16 via permlane16_swap
        acc[0] = xorsum32(acc[0]);        // xor32 via permlane32_swap

        // combo layout within each 4-lane group (quad base):
        // +0: i(row rb), +1: g, +2: f, +3: o  (rb = (lane>>2)&1)
        float gi = movdpp<0x00>(acc[0]);  // quad bcast lane0
        float gg = movdpp<0x55>(acc[0]);  // quad bcast lane1
        float gf = movdpp<0xAA>(acc[0]);  // quad bcast lane2
        float go = movdpp<0xFF>(acc[0]);  // quad bcast lane3
        float i_ = sigm(gi + bi), f_ = sigm(gf + bf_), g_ = tanh_fast(gg + bg), o_ = sigm(go + bo);
        c_state = f_ * c_state + i_ * g_;
        float hval = o_ * tanh_fast(c_state);  // lanes 0-3: row0, lanes 4-7: row1 (replicated)

        // h1 (a row1 value) into lane 0 via row_ror:4
        float h1 = movdpp<0x124>(hval);
        if (lane == 0) {
            unsigned long long v = ((unsigned long long)packf16(hval, h1) << 32) | (uint32_t)s;
            ASTORE(&hbuf[((s & 1) << 10) + b * 4 + q], v);
            if (s == 8192) { hf32[hb + 2 * q] = hval; hf32[hb + 2 * q + 1] = h1; }
        }
    }
}

// ---------------- kernel 2: pred = h_last @ W_lin^T + b_lin ----------------
__global__ __launch_bounds__(256) void final_linear(const float* __restrict__ hf,
                                                    const float* __restrict__ Wlin,
                                                    const float* __restrict__ blin,
                                                    float* __restrict__ out) {
    const int row = blockIdx.x * 4 + (threadIdx.x >> 6);
    const int lane = threadIdx.x & 63;
    float acc = 0.f;
#pragma unroll
    for (int it = 0; it < 8; it++) {
        int c = it * 256 + lane * 4;
        float4 wv = *(const float4*)&Wlin[(size_t)row * 2048 + c];
        float4 hv = *(const float4*)&hf[c];
        acc += wv.x * hv.x + wv.y * hv.y + wv.z * hv.z + wv.w * hv.w;
    }
#pragma unroll
    for (int off = 32; off; off >>= 1) acc += __shfl_xor(acc, off, 64);
    if (lane == 0) out[row] = acc + blin[row];
}

// ---------------- launch ----------------
extern "C" void kernel_launch(void* const* d_in, const int* in_sizes, int n_in,
                              void* d_out, int out_size, void* d_ws, size_t ws_size,
                              hipStream_t stream) {
    const float* seq  = (const float*)d_in[0];
    const float* Wih  = (const float*)d_in[1];
    const float* Whh  = (const float*)d_in[2];
    const float* bih  = (const float*)d_in[3];
    const float* bhh  = (const float*)d_in[4];
    const float* h0   = (const float*)d_in[5];
    const float* c0   = (const float*)d_in[6];
    const float* Wlin = (const float*)d_in[7];
    const float* blin = (const float*)d_in[8];
    float* out = (float*)d_out;

    char* ws = (char*)d_ws;
    unsigned long long* hbuf = (unsigned long long*)ws;  // 2*1024*8 = 16 KiB
    float* hf32 = (float*)(ws + 16384);                  // 8 KiB

    init_hbuf<<<8, 256, 0, stream>>>(hbuf);
    lstm_persist<<<256, 256, 0, stream>>>(seq, Wih, Whh, bih, bhh, h0, c0, hbuf, hf32);
    final_linear<<<128, 256, 0, stream>>>(hf32, Wlin, blin, out);
}

// Round 10
// 14241.844 us; speedup vs baseline: 1.0830x; 1.0830x over previous
//
#include <hip/hip_runtime.h>
#include <hip/hip_bf16.h>
#include <stdint.h>

// Problem: IN=512, H=2048, OUT=512, T=8192. Gate rows 4H=8192.
// Persistent-RNN: 256 blocks x 256 threads (4 waves), 1 block/CU, [W_ih|W_hh]
// in VGPRs as f16 pairs (160 u32/lane). h exchanged device-wide as
// step-tagged u64 ({f16 pair | step}) via L3, sc0 sc1 asm polls.
// Round 20 = EXACT REVERT to r17 champion (13.98ms). r19's adaptive
// pre-sleep regressed +10% (and produced a 35ms outlier dispatch):
//   LAW (r19, generalizes r16): NO open-loop or adaptive delays anywhere in
//   the step. Per-block timing adaptation random-walks independently; an
//   overshooting block delays its publish, its watchers' detects, and their
//   adaptation in turn — variance feeds forward in this max-coupled system.
//   Only reactive polling at fixed cadence is admissible.
// SESSION STATE: every axis has a measured boundary. This kernel sits at a
// structural sync-latency floor (~4100cy/step = ~1300cy VALU + ~2800cy
// device-wide exchange), NOT a memory/compute roofline (HBM 0.56%, VALU 31%).
// LAWS (hard-won, do not revisit):
//   r19: no adaptive/open-loop delays (above).
//   r18: poll loads stay fully coalesced (16B/lane contiguous across the
//     wave); don't loosen the sleep throttle past sweep 4. (+4% otherwise)
//   r16: publish lockstep via in-loop __syncthreads is LOAD-BEARING; flag/
//     rotation protocols spread publish variance, it feeds forward (+68%).
//   r15: dot2 == pk_fma issue rate; 128 dot2 is the h-dot VALU floor.
//   r14: never exit a spin with un-waited loads (VMEM writeback clobbers
//     freed regs); no pipelined 2-set polls (stray set force-drained by the
//     barrier's vmcnt(0) anyway).
//   r11: __hip_atomic_load(RELAXED,AGENT) does NOT emit sc0 -> stale L1
//     polls. Spin must use asm global_load_dwordx4 sc0 sc1.
//   r7/r9: arch VGPRs cap at 256/wave; 160 weight regs fit ONLY with
//     256-thread blocks; no 512-thread or 320-reg variants.
//   (analysis) MFMA matvec h-dot: B-fragment layout forces ~64 ds_read_b128
//     per lane vs 4 today -> LDS-bound, strictly worse. Closed.

// ---------------- helpers ----------------

__device__ __forceinline__ uint32_t packf16(float a, float b) {
    // v_cvt_pkrtz_f16_f32: a -> low16, b -> high16 (RTZ)
    auto h = __builtin_amdgcn_cvt_pkrtz(a, b);
    return __builtin_bit_cast(uint32_t, h);
}

__device__ __forceinline__ float dot2h(uint32_t a, uint32_t b, float c) {
    float d;
    asm("v_dot2_f32_f16 %0, %1, %2, %3" : "=v"(d) : "v"(a), "v"(b), "v"(c));
    return d;
}

template <int CTRL>
__device__ __forceinline__ float movdpp(float x) {
    return __int_as_float(__builtin_amdgcn_mov_dpp(__float_as_int(x), CTRL, 0xF, 0xF, true));
}

// acc += shfl_xor(acc,16) via v_permlane16_swap (a'={r0,r0,r2,r2}, b'={r1,r1,r3,r3})
__device__ __forceinline__ float xorsum16(float x) {
#if __has_builtin(__builtin_amdgcn_permlane16_swap)
    auto r = __builtin_amdgcn_permlane16_swap(__float_as_uint(x), __float_as_uint(x), false, false);
    return __uint_as_float(r[0]) + __uint_as_float(r[1]);
#else
    return x + __shfl_xor(x, 16, 64);
#endif
}

// acc += shfl_xor(acc,32) via v_permlane32_swap (a'={lo,lo}, b'={hi,hi})
__device__ __forceinline__ float xorsum32(float x) {
#if __has_builtin(__builtin_amdgcn_permlane32_swap)
    auto r = __builtin_amdgcn_permlane32_swap(__float_as_uint(x), __float_as_uint(x), false, false);
    return __uint_as_float(r[0]) + __uint_as_float(r[1]);
#else
    return x + __shfl_xor(x, 32, 64);
#endif
}

__device__ __forceinline__ float sigm(float x) { return 1.f / (1.f + __expf(-x)); }
__device__ __forceinline__ float tanh_fast(float x) { return 1.f - 2.f / (1.f + __expf(2.f * x)); }

#define ASTORE(p, v) __hip_atomic_store((p), (v), __ATOMIC_RELAXED, __HIP_MEMORY_SCOPE_AGENT)

// Issue two 16B device-scope loads (bypass L1/L2 via sc0 sc1), NO wait.
// Tear-safe: each contained u64 carries its own tag in the low 32 bits.
__device__ __forceinline__ void poll_issue(const unsigned long long* pa,
                                           const unsigned long long* pb,
                                           ulonglong2& ra, ulonglong2& rb) {
    asm volatile(
        "global_load_dwordx4 %0, %2, off sc0 sc1\n\t"
        "global_load_dwordx4 %1, %3, off sc0 sc1"
        : "=v"(ra), "=v"(rb)
        : "v"(pa), "v"(pb)
        : "memory");
    __builtin_amdgcn_sched_barrier(0);  // keep dependent VALU below the issue
}

// Reissue a single 16B half (used by the sticky spin on unmatched halves only).
__device__ __forceinline__ void poll_issue_one(const unsigned long long* p, ulonglong2& r) {
    asm volatile("global_load_dwordx4 %0, %1, off sc0 sc1"
                 : "=v"(r) : "v"(p) : "memory");
}

__device__ __forceinline__ void poll_wait() {
    asm volatile("s_waitcnt vmcnt(0)" ::: "memory");
    __builtin_amdgcn_sched_barrier(0);  // rule #18: stop reg-only hoisting past waitcnt
}

// ---------------- kernel 0: invalidate tags ----------------
__global__ __launch_bounds__(256) void init_hbuf(unsigned long long* hbuf) {
    int i = blockIdx.x * 256 + threadIdx.x;
    if (i < 2048) hbuf[i] = ~0ull;  // tag 0xFFFFFFFF never matches a step index
}

// ---------------- kernel 1: persistent LSTM recurrence ----------------
// Block b owns h indices [8b, 8b+8). Wave q owns rows {hb+2q, hb+2q+1}, ALL 4
// gates (combo c = gate*2 + rowbit). Weights: 160 packed f16 VGPRs/lane
// (k<4 = W_ih, else W_hh remapped: w[c*20+4+4j+i] <-> h pair 256j+4*lane+i).
// Spin: wave q polls pairs [256q,256q+256): lane L watches pairs {256q+2L,
// 256q+2L+1} and {256q+128+2L, +1} via 2 coalesced dwordx4, sticky per-half.
__global__ __launch_bounds__(256, 1) void lstm_persist(const float* __restrict__ seq,
                                                       const float* __restrict__ Wih,
                                                       const float* __restrict__ Whh,
                                                       const float* __restrict__ bih,
                                                       const float* __restrict__ bhh,
                                                       const float* __restrict__ h0,
                                                       const float* __restrict__ c0,
                                                       unsigned long long* hbuf,
                                                       float* __restrict__ hf32) {
    const int b = blockIdx.x, tid = threadIdx.x;
    const int q = tid >> 6, lane = tid & 63;
    const int hb = b * 8;
    const int rb = (lane >> 2) & 1;       // this lane's row within the wave's pair
    const int myrow = hb + 2 * q + rb;

    // ---- preload [W_ih | W_hh] rows for all 4 gates of rows {2q, 2q+1} ----
    uint32_t w[160];
#pragma unroll
    for (int c = 0; c < 8; c++) {
        const int R = (c >> 1) * 2048 + hb + 2 * q + (c & 1);
        const float2* rih = (const float2*)(Wih + (size_t)R * 512);
        const float2* rhh = (const float2*)(Whh + (size_t)R * 2048);
#pragma unroll
        for (int k = 0; k < 4; k++) {
            float2 v = rih[k * 64 + lane];
            w[c * 20 + k] = packf16(v.x, v.y);
        }
        // W_hh remap to match the b128 h-dot: w[c*20+4+4j+i] <-> h pair 256j+4*lane+i
#pragma unroll
        for (int j = 0; j < 4; j++)
#pragma unroll
            for (int i = 0; i < 4; i++) {
                float2 v = rhh[256 * j + 4 * lane + i];
                w[c * 20 + 4 + 4 * j + i] = packf16(v.x, v.y);
            }
    }

    __shared__ alignas(16) uint32_t v_stage[2][1024];  // h_{t-1} pairs, parity double-buffered

    // per-lane (replicated) bias + c state for row `myrow`
    const float bi  = bih[myrow] + bhh[myrow];
    const float bf_ = bih[2048 + myrow] + bhh[2048 + myrow];
    const float bg  = bih[4096 + myrow] + bhh[4096 + myrow];
    const float bo  = bih[6144 + myrow] + bhh[6144 + myrow];
    float c_state = c0[myrow];

    // publish h0 slice with tag 0 (parity 0)
    if (q == 0 && lane < 4) {
        float a = h0[hb + lane * 2], b2 = h0[hb + lane * 2 + 1];
        unsigned long long v = ((unsigned long long)packf16(a, b2) << 32);
        ASTORE(&hbuf[b * 4 + lane], v);
    }

    // prefetch x_0: lane owns x pairs {k*64+lane : k in [0,4)}
    float2 xn[4];
#pragma unroll
    for (int k = 0; k < 4; k++) xn[k] = ((const float2*)seq)[k * 64 + lane];

    int gave_up = 0;

    for (int s = 1; s <= 8192; s++) {
        const int t = s - 1, bs = t & 1;
        const uint32_t want = (uint32_t)t;

        // ---- pack x_t (compiler drains the x prefetch here, BEFORE poll issue) ----
        uint32_t x0 = packf16(xn[0].x, xn[0].y), x1 = packf16(xn[1].x, xn[1].y);
        uint32_t x2 = packf16(xn[2].x, xn[2].y), x3 = packf16(xn[3].x, xn[3].y);
        __builtin_amdgcn_sched_barrier(0);  // pin pack (and its waitcnt) above poll issue

        // ---- early poll issue: first sweep's RTT overlaps the x-dot ----
        const unsigned long long* base = hbuf + (bs << 10) + q * 256;
        const unsigned long long* pa = base + 2 * lane;        // pairs 2L, 2L+1
        const unsigned long long* pb = base + 128 + 2 * lane;  // pairs 128+2L, +1
        ulonglong2 ra, rb2;
        poll_issue(pa, pb, ra, rb2);

        // ---- x-part of dot from registers (VALU-only, hides first poll RTT) ----
        float acc[8];
#pragma unroll
        for (int c = 0; c < 8; c++) {
            float a = dot2h(w[c * 20 + 0], x0, 0.f);
            a = dot2h(w[c * 20 + 1], x1, a);
            a = dot2h(w[c * 20 + 2], x2, a);
            acc[c] = dot2h(w[c * 20 + 3], x3, a);
        }

        // ---- distributed spin, sticky halves: once a 16B half's two tags
        // match (monotonic within the step), stop re-loading it; reissue
        // only unmatched halves. Every sweep starts with vmcnt(0); no exit
        // with un-waited loads. ----
        if (!gave_up) {
            int tries = 0;
            bool oka = false, okb = false;
            for (;;) {
                poll_wait();
                oka = oka | (((uint32_t)ra.x == want) & ((uint32_t)ra.y == want));
                okb = okb | (((uint32_t)rb2.x == want) & ((uint32_t)rb2.y == want));
                if (__all(oka & okb)) break;
                if (++tries > (1 << 17)) { gave_up = 1; break; }  // diagnostic fuse
                if (!oka) poll_issue_one(pa, ra);                 // reissue misses only
                if (!okb) poll_issue_one(pb, rb2);
                __builtin_amdgcn_sched_barrier(0);
                if (tries > 2) __builtin_amdgcn_s_sleep(1);       // sleep overlaps RTT
            }
        } else {
            poll_wait();  // loop-top issue acts as the once-per-iter refresh
        }

        // ---- stage payload -> LDS (identity pair layout: two b64 stores) ----
        {
            uint2* vsa = (uint2*)&v_stage[bs][q * 256 + 2 * lane];
            uint2* vsb = (uint2*)&v_stage[bs][q * 256 + 128 + 2 * lane];
            *vsa = make_uint2((uint32_t)(ra.x >> 32), (uint32_t)(ra.y >> 32));
            *vsb = make_uint2((uint32_t)(rb2.x >> 32), (uint32_t)(rb2.y >> 32));
        }

        __syncthreads();  // B1: v_stage[bs] ready (cheap: nothing in vmcnt)

        // prefetch x_{t+1} AFTER the barrier: drains under the h-dot,
        // off both the spin path and the barrier's vmcnt(0) drain.
        if (s < 8192) {
            const float2* xp = (const float2*)(seq + (size_t)s * 512);
#pragma unroll
            for (int k = 0; k < 4; k++) xn[k] = xp[k * 64 + lane];
        }

        // ---- h-part of dot: 4 quarters x b128; lane L reads pairs 256j+4L+{0..3} ----
#pragma unroll
        for (int j = 0; j < 4; j++) {
            const uint4 hv = *(const uint4*)&v_stage[bs][256 * j + 4 * lane];
#pragma unroll
            for (int c = 0; c < 8; c++) {
                float a = dot2h(w[c * 20 + 4 + 4 * j + 0], hv.x, acc[c]);
                a = dot2h(w[c * 20 + 4 + 4 * j + 1], hv.y, a);
                a = dot2h(w[c * 20 + 4 + 4 * j + 2], hv.z, a);
                acc[c] = dot2h(w[c * 20 + 4 + 4 * j + 3], hv.w, a);
            }
        }

        // ---- fold 8 accs -> 1; DPP/permlane forms (only xor4 keeps DS).
        // Lane L holds combo c(L&7) = 4*(L&1) + 2*((L>>1)&1) + ((L>>2)&1),
        // replicated every 8 lanes ----
#pragma unroll
        for (int j = 0; j < 4; j++) {  // d=1: 8 -> 4 (quad_perm xor1 = 0xB1)
            float lo = acc[j], hi = acc[j + 4];
            float sel = (lane & 1) ? lo : hi;
            float got = movdpp<0xB1>(sel);
            acc[j] = ((lane & 1) ? hi : lo) + got;
        }
#pragma unroll
        for (int j = 0; j < 2; j++) {  // d=2: 4 -> 2 (quad_perm xor2 = 0x4E)
            float lo = acc[j], hi = acc[j + 2];
            float sel = (lane & 2) ? lo : hi;
            float got = movdpp<0x4E>(sel);
            acc[j] = ((lane & 2) ? hi : lo) + got;
        }
        {  // d=4: 2 -> 1 (no DPP form for xor4; keep ds shuffle)
            float lo = acc[0], hi = acc[1];
            float sel = (lane & 4) ? lo : hi;
            float got = __shfl_xor(sel, 4, 64);
            acc[0] = ((lane & 4) ? hi : lo) + got;
        }
        acc[0] += movdpp<0x128>(acc[0]);  // xor8 via row_ror:8
        acc[0] = xorsum16(acc[0]);        // xor16 via permlane16_swap
        acc[0] = xorsum32(acc[0]);        // xor32 via permlane32_swap

        // combo layout within each 4-lane group (quad base):
        // +0: i(row rb), +1: g, +2: f, +3: o  (rb = (lane>>2)&1)
        float gi = movdpp<0x00>(acc[0]);  // quad bcast lane0
        float gg = movdpp<0x55>(acc[0]);  // quad bcast lane1
        float gf = movdpp<0xAA>(acc[0]);  // quad bcast lane2
        float go = movdpp<0xFF>(acc[0]);  // quad bcast lane3
        float i_ = sigm(gi + bi), f_ = sigm(gf + bf_), g_ = tanh_fast(gg + bg), o_ = sigm(go + bo);
        c_state = f_ * c_state + i_ * g_;
        float hval = o_ * tanh_fast(c_state);  // lanes 0-3: row0, lanes 4-7: row1 (replicated)

        // h1 (a row1 value) into lane 0 via row_ror:4
        float h1 = movdpp<0x124>(hval);
        if (lane == 0) {
            unsigned long long v = ((unsigned long long)packf16(hval, h1) << 32) | (uint32_t)s;
            ASTORE(&hbuf[((s & 1) << 10) + b * 4 + q], v);
            if (s == 8192) { hf32[hb + 2 * q] = hval; hf32[hb + 2 * q + 1] = h1; }
        }
    }
}

// ---------------- kernel 2: pred = h_last @ W_lin^T + b_lin ----------------
__global__ __launch_bounds__(256) void final_linear(const float* __restrict__ hf,
                                                    const float* __restrict__ Wlin,
                                                    const float* __restrict__ blin,
                                                    float* __restrict__ out) {
    const int row = blockIdx.x * 4 + (threadIdx.x >> 6);
    const int lane = threadIdx.x & 63;
    float acc = 0.f;
#pragma unroll
    for (int it = 0; it < 8; it++) {
        int c = it * 256 + lane * 4;
        float4 wv = *(const float4*)&Wlin[(size_t)row * 2048 + c];
        float4 hv = *(const float4*)&hf[c];
        acc += wv.x * hv.x + wv.y * hv.y + wv.z * hv.z + wv.w * hv.w;
    }
#pragma unroll
    for (int off = 32; off; off >>= 1) acc += __shfl_xor(acc, off, 64);
    if (lane == 0) out[row] = acc + blin[row];
}

// ---------------- launch ----------------
extern "C" void kernel_launch(void* const* d_in, const int* in_sizes, int n_in,
                              void* d_out, int out_size, void* d_ws, size_t ws_size,
                              hipStream_t stream) {
    const float* seq  = (const float*)d_in[0];
    const float* Wih  = (const float*)d_in[1];
    const float* Whh  = (const float*)d_in[2];
    const float* bih  = (const float*)d_in[3];
    const float* bhh  = (const float*)d_in[4];
    const float* h0   = (const float*)d_in[5];
    const float* c0   = (const float*)d_in[6];
    const float* Wlin = (const float*)d_in[7];
    const float* blin = (const float*)d_in[8];
    float* out = (float*)d_out;

    char* ws = (char*)d_ws;
    unsigned long long* hbuf = (unsigned long long*)ws;  // 2*1024*8 = 16 KiB
    float* hf32 = (float*)(ws + 16384);                  // 8 KiB

    init_hbuf<<<8, 256, 0, stream>>>(hbuf);
    lstm_persist<<<256, 256, 0, stream>>>(seq, Wih, Whh, bih, bhh, h0, c0, hbuf, hf32);
    final_linear<<<128, 256, 0, stream>>>(hf32, Wlin, blin, out);
}